// Round 2
// baseline (5313.073 us; speedup 1.0000x reference)
//
#include <hip/hip_runtime.h>

#define NUM_NODES 20000
#define NUM_EDGES 320000
#define NODE_DIM  256
#define EDGE_DIM  64
#define HIDDEN    512
#define K_EDGE    576   // 2*NODE_DIM + EDGE_DIM
#define K_NODE    768   // NODE_DIM + HIDDEN

typedef short  s16x8  __attribute__((ext_vector_type(8)));
typedef float  f32x16 __attribute__((ext_vector_type(16)));

__device__ __forceinline__ unsigned short f2bf(float f) {
    union { float f; unsigned u; } c; c.f = f;
    unsigned r = c.u + 0x7fffu + ((c.u >> 16) & 1u);   // RNE
    return (unsigned short)(r >> 16);
}
__device__ __forceinline__ float bf2f(unsigned short b) {
    union { unsigned u; float f; } c; c.u = ((unsigned)b) << 16;
    return c.f;
}
// k-permutation within each 16-block: swap bit2 <-> bit3.
// Element order of an MFMA A/B frag (32x32x16 bf16): vector elem i holds
// k = 4*(lane>>5) + (i&3) + 8*(i>>2).  Storing k at permuted position
// swapmid(k) makes the 8 frag elements contiguous: positions 8g..8g+7.
__device__ __forceinline__ int swapmid(int x) {
    return (x & 3) | ((x & 4) << 1) | ((x & 8) >> 1);
}
__device__ __forceinline__ float f4c(const float4 v, int i) {
    switch (i) { case 0: return v.x; case 1: return v.y; case 2: return v.z; default: return v.w; }
}

// ---------------- weight prep: fp32 [K][N] -> bf16 hi/lo planes in
// [k-block][n][16 permuted k] layout (A-operand-frag-ready) ----------------
__global__ void prep_weights(const float* __restrict__ W1, const float* __restrict__ W2,
                             unsigned short* __restrict__ w1h, unsigned short* __restrict__ w1l,
                             unsigned short* __restrict__ w2h, unsigned short* __restrict__ w2l)
{
    const int total1 = K_EDGE * HIDDEN;    // 294912
    const int total2 = HIDDEN * HIDDEN;    // 262144
    for (int idx = blockIdx.x * 256 + threadIdx.x; idx < total1 + total2;
         idx += gridDim.x * 256) {
        const float* W; unsigned short *dh, *dl; int k, n;
        if (idx < total1) { W = W1; dh = w1h; dl = w1l; k = idx >> 9; n = idx & 511; }
        else { int j = idx - total1; W = W2; dh = w2h; dl = w2l; k = j >> 9; n = j & 511; }
        float w = W[k * HIDDEN + n];
        unsigned short h = f2bf(w);
        unsigned short l = f2bf(w - bf2f(h));
        int d = (k >> 4) * (HIDDEN * 16) + n * 16 + swapmid(k & 15);
        dh[d] = h; dl[d] = l;
    }
}

// ---------------- edge kernel: MFMA, operand-swapped ----------------
// Per block: 64 edges. D1'[h][e] = W1^T (A) * X^T (B); relu -> H in LDS;
// D2'[n2][e] = W2^T * H^T; atomicAdd into agg[tgt[e]][n2].
// 8 waves x 64-row (h / n2) slice; each wave covers all 64 edges (2 N-tiles).
__global__ __launch_bounds__(512, 2)
void edge_mlp_mfma(const float* __restrict__ nf,
                   const int* __restrict__ src_idx, const int* __restrict__ tgt_idx,
                   const float* __restrict__ ef,
                   const unsigned short* __restrict__ w1h, const unsigned short* __restrict__ w1l,
                   const unsigned short* __restrict__ w2h, const unsigned short* __restrict__ w2l,
                   const float* __restrict__ b1, const float* __restrict__ b2,
                   float* __restrict__ agg)
{
    // X: hi @0 (64*576*2=73728 B), lo @73728  (row stride 1152 B = 9*128)
    // H (overlaid after layer 1): hi @0 (64*512*2=65536), lo @65536 (stride 1024)
    extern __shared__ char smem[];
    const int tid = threadIdx.x;
    const int eb  = blockIdx.x * 64;

    const float4* nf4 = reinterpret_cast<const float4*>(nf);
    const float4* ef4 = reinterpret_cast<const float4*>(ef);

    // ---- stage X = [nf[src] | nf[tgt] | ef] as bf16 hi/lo, k-permuted + XOR-swizzled ----
    auto stash = [&](int e, int c, float4 v) {
        int cpp = (c & ~15) | swapmid(c & 15);          // c is 4-aligned -> quad stays contiguous
        int off = e * 1152 + ((cpp * 2) ^ ((e & 7) << 4));
        unsigned short h0 = f2bf(v.x), h1 = f2bf(v.y), h2 = f2bf(v.z), h3 = f2bf(v.w);
        uint2 uh; uh.x = h0 | ((unsigned)h1 << 16); uh.y = h2 | ((unsigned)h3 << 16);
        uint2 ul;
        ul.x = f2bf(v.x - bf2f(h0)) | ((unsigned)f2bf(v.y - bf2f(h1)) << 16);
        ul.y = f2bf(v.z - bf2f(h2)) | ((unsigned)f2bf(v.w - bf2f(h3)) << 16);
        *reinterpret_cast<uint2*>(smem + off)         = uh;
        *reinterpret_cast<uint2*>(smem + 73728 + off) = ul;
    };
    for (int i = tid; i < 64 * 64; i += 512) {          // src cols 0-255, tgt cols 256-511
        int e = i >> 6, q = i & 63;
        int s = src_idx[eb + e];
        stash(e, 4 * q, nf4[(size_t)s * 64 + q]);
        int t = tgt_idx[eb + e];
        stash(e, 256 + 4 * q, nf4[(size_t)t * 64 + q]);
    }
    for (int i = tid; i < 64 * 16; i += 512) {          // ef cols 512-575
        int e = i >> 4, q = i & 15;
        stash(e, 512 + 4 * q, ef4[(size_t)(eb + e) * 16 + q]);
    }
    __syncthreads();

    const int w  = tid >> 6;          // wave 0..7 -> h/n2 slice [64w, 64w+64)
    const int l  = tid & 63;
    const int le = l & 31;
    const int g  = l >> 5;
    const int n0 = w * 64 + le;       // A-frag row (+32 per m-tile)

    const s16x8* A1h = reinterpret_cast<const s16x8*>(w1h);
    const s16x8* A1l = reinterpret_cast<const s16x8*>(w1l);
    const s16x8* A2h = reinterpret_cast<const s16x8*>(w2h);
    const s16x8* A2l = reinterpret_cast<const s16x8*>(w2l);

    f32x16 acc[2][2];
    #pragma unroll
    for (int mt = 0; mt < 2; ++mt)
        #pragma unroll
        for (int nt = 0; nt < 2; ++nt)
            #pragma unroll
            for (int i = 0; i < 16; ++i) acc[mt][nt][i] = 0.0f;

    // ---- layer 1: K = 576 (36 k-steps), A = W1^T (global), B = X^T (LDS) ----
    auto l1_load = [&](s16x8 (&AH)[2], s16x8 (&AL)[2], int blk) {
        #pragma unroll
        for (int mt = 0; mt < 2; ++mt) {
            int idx = blk * 1024 + (n0 + 32 * mt) * 2 + g;
            AH[mt] = A1h[idx]; AL[mt] = A1l[idx];
        }
    };
    auto l1_comp = [&](const s16x8 (&AH)[2], const s16x8 (&AL)[2], int ks) {
        const int kbyte = ks * 32 + 16 * g;
        s16x8 Bh[2], Bl[2];
        #pragma unroll
        for (int nt = 0; nt < 2; ++nt) {
            int e = 32 * nt + le;
            int off = e * 1152 + (kbyte ^ ((e & 7) << 4));
            Bh[nt] = *reinterpret_cast<const s16x8*>(smem + off);
            Bl[nt] = *reinterpret_cast<const s16x8*>(smem + 73728 + off);
        }
        #pragma unroll
        for (int mt = 0; mt < 2; ++mt)
            #pragma unroll
            for (int nt = 0; nt < 2; ++nt)
                acc[mt][nt] = __builtin_amdgcn_mfma_f32_32x32x16_bf16(AH[mt], Bh[nt], acc[mt][nt], 0, 0, 0);
        #pragma unroll
        for (int mt = 0; mt < 2; ++mt)
            #pragma unroll
            for (int nt = 0; nt < 2; ++nt)
                acc[mt][nt] = __builtin_amdgcn_mfma_f32_32x32x16_bf16(AH[mt], Bl[nt], acc[mt][nt], 0, 0, 0);
        #pragma unroll
        for (int mt = 0; mt < 2; ++mt)
            #pragma unroll
            for (int nt = 0; nt < 2; ++nt)
                acc[mt][nt] = __builtin_amdgcn_mfma_f32_32x32x16_bf16(AL[mt], Bh[nt], acc[mt][nt], 0, 0, 0);
    };
    {
        s16x8 Ah0[2], Al0[2], Ah1[2], Al1[2];
        l1_load(Ah0, Al0, 0);
        for (int ks = 0; ks < 36; ks += 2) {
            l1_load(Ah1, Al1, ks + 1);
            l1_comp(Ah0, Al0, ks);
            if (ks + 2 < 36) l1_load(Ah0, Al0, ks + 2);
            l1_comp(Ah1, Al1, ks + 1);
        }
    }

    __syncthreads();   // everyone done reading X; overlay H

    // ---- bias + relu -> H (bf16 hi/lo) into LDS, A/B-frag-ready layout ----
    #pragma unroll
    for (int mt = 0; mt < 2; ++mt) {
        const int hbase = w * 64 + 32 * mt + 4 * g;
        float4 b1q[4];
        #pragma unroll
        for (int rq = 0; rq < 4; ++rq)
            b1q[rq] = *reinterpret_cast<const float4*>(&b1[hbase + 8 * rq]);
        #pragma unroll
        for (int nt = 0; nt < 2; ++nt) {
            const int e = 32 * nt + le;
            #pragma unroll
            for (int rq = 0; rq < 4; ++rq) {
                unsigned short hh[4], ll[4];
                #pragma unroll
                for (int j = 0; j < 4; ++j) {
                    float x = fmaxf(acc[mt][nt][4 * rq + j] + f4c(b1q[rq], j), 0.0f);
                    hh[j] = f2bf(x);
                    ll[j] = f2bf(x - bf2f(hh[j]));
                }
                int cq  = (4 * w + 2 * mt + (rq >> 1)) * 16 + 4 * (rq & 1) + 8 * g;
                int off = e * 1024 + ((cq * 2) ^ ((e & 7) << 4));
                uint2 uh; uh.x = hh[0] | ((unsigned)hh[1] << 16); uh.y = hh[2] | ((unsigned)hh[3] << 16);
                uint2 ul; ul.x = ll[0] | ((unsigned)ll[1] << 16); ul.y = ll[2] | ((unsigned)ll[3] << 16);
                *reinterpret_cast<uint2*>(smem + off)         = uh;
                *reinterpret_cast<uint2*>(smem + 65536 + off) = ul;
            }
        }
    }
    __syncthreads();

    // ---- layer 2: K = 512 (32 k-steps), A = W2^T (global), B = H^T (LDS) ----
    f32x16 acc2[2][2];
    #pragma unroll
    for (int mt = 0; mt < 2; ++mt)
        #pragma unroll
        for (int nt = 0; nt < 2; ++nt)
            #pragma unroll
            for (int i = 0; i < 16; ++i) acc2[mt][nt][i] = 0.0f;

    auto l2_load = [&](s16x8 (&AH)[2], s16x8 (&AL)[2], int blk) {
        #pragma unroll
        for (int mt = 0; mt < 2; ++mt) {
            int idx = blk * 1024 + (n0 + 32 * mt) * 2 + g;
            AH[mt] = A2h[idx]; AL[mt] = A2l[idx];
        }
    };
    auto l2_comp = [&](const s16x8 (&AH)[2], const s16x8 (&AL)[2], int ks) {
        const int kbyte = ks * 32 + 16 * g;
        s16x8 Bh[2], Bl[2];
        #pragma unroll
        for (int nt = 0; nt < 2; ++nt) {
            int e = 32 * nt + le;
            int off = e * 1024 + (kbyte ^ ((e & 7) << 4));
            Bh[nt] = *reinterpret_cast<const s16x8*>(smem + off);
            Bl[nt] = *reinterpret_cast<const s16x8*>(smem + 65536 + off);
        }
        #pragma unroll
        for (int mt = 0; mt < 2; ++mt)
            #pragma unroll
            for (int nt = 0; nt < 2; ++nt)
                acc2[mt][nt] = __builtin_amdgcn_mfma_f32_32x32x16_bf16(AH[mt], Bh[nt], acc2[mt][nt], 0, 0, 0);
        #pragma unroll
        for (int mt = 0; mt < 2; ++mt)
            #pragma unroll
            for (int nt = 0; nt < 2; ++nt)
                acc2[mt][nt] = __builtin_amdgcn_mfma_f32_32x32x16_bf16(AH[mt], Bl[nt], acc2[mt][nt], 0, 0, 0);
        #pragma unroll
        for (int mt = 0; mt < 2; ++mt)
            #pragma unroll
            for (int nt = 0; nt < 2; ++nt)
                acc2[mt][nt] = __builtin_amdgcn_mfma_f32_32x32x16_bf16(AL[mt], Bh[nt], acc2[mt][nt], 0, 0, 0);
    };
    {
        s16x8 Ah0[2], Al0[2], Ah1[2], Al1[2];
        l2_load(Ah0, Al0, 0);
        for (int ks = 0; ks < 32; ks += 2) {
            l2_load(Ah1, Al1, ks + 1);
            l2_comp(Ah0, Al0, ks);
            if (ks + 2 < 32) l2_load(Ah0, Al0, ks + 2);
            l2_comp(Ah1, Al1, ks + 1);
        }
    }

    // ---- epilogue: + b2, atomic scatter-add into agg[tgt[e]] ----
    #pragma unroll
    for (int nt = 0; nt < 2; ++nt) {
        const int t = tgt_idx[eb + 32 * nt + le];
        float* dst = agg + (size_t)t * HIDDEN;
        #pragma unroll
        for (int mt = 0; mt < 2; ++mt) {
            const int nbase = w * 64 + 32 * mt + 4 * g;
            #pragma unroll
            for (int rq = 0; rq < 4; ++rq) {
                float4 b2q = *reinterpret_cast<const float4*>(&b2[nbase + 8 * rq]);
                #pragma unroll
                for (int j = 0; j < 4; ++j)
                    atomicAdd(dst + nbase + 8 * rq + j, acc2[mt][nt][4 * rq + j] + f4c(b2q, j));
            }
        }
    }
}

// ---------------- node kernel (fp32 VALU, unchanged structure) ----------------
__global__ __launch_bounds__(256, 2)
void node_mlp_kernel(const float* __restrict__ nf,
                     const float* __restrict__ agg,
                     const float* __restrict__ W3, const float* __restrict__ b3,
                     const float* __restrict__ W4, const float* __restrict__ b4,
                     float* __restrict__ out)
{
    __shared__ float sX[16 * K_NODE];   // 49152 B; reused as sG[16*HIDDEN]
    __shared__ float sW[8 * HIDDEN];    // 16384 B

    const int tid = threadIdx.x;
    const int rb  = blockIdx.x * 16;

    const float4* nf4  = reinterpret_cast<const float4*>(nf);
    const float4* agg4 = reinterpret_cast<const float4*>(agg);
    float4* sX4 = reinterpret_cast<float4*>(sX);
    float4* sW4 = reinterpret_cast<float4*>(sW);

    for (int i = tid; i < 16 * 64; i += 256) {
        int r = i >> 6, q = i & 63;
        sX4[r * 192 + q] = nf4[(size_t)(rb + r) * 64 + q];
    }
    for (int i = tid; i < 16 * 128; i += 256) {
        int r = i >> 7, q = i & 127;
        sX4[r * 192 + 64 + q] = agg4[(size_t)(rb + r) * 128 + q];
    }

    const int cg    = tid & 63;
    const int er    = (tid >> 6) & 1;
    const int ch    = tid >> 7;
    const int rbase = er * 8;
    const int cbase = ch * 256 + cg;

    float acc[8][4] = {};

    for (int kb = 0; kb < K_NODE; kb += 8) {
        __syncthreads();
        const float4* w4 = reinterpret_cast<const float4*>(W3 + (size_t)kb * HIDDEN);
        for (int i = tid; i < 1024; i += 256) sW4[i] = w4[i];
        __syncthreads();
        #pragma unroll
        for (int kq = 0; kq < 2; ++kq) {
            float4 xq[8];
            #pragma unroll
            for (int m = 0; m < 8; ++m)
                xq[m] = sX4[(rbase + m) * 192 + (kb >> 2) + kq];
            #pragma unroll
            for (int kc = 0; kc < 4; ++kc) {
                const int k = kq * 4 + kc;
                float wv[4];
                #pragma unroll
                for (int j = 0; j < 4; ++j) wv[j] = sW[k * HIDDEN + cbase + j * 64];
                #pragma unroll
                for (int m = 0; m < 8; ++m)
                    #pragma unroll
                    for (int j = 0; j < 4; ++j)
                        acc[m][j] = fmaf(f4c(xq[m], kc), wv[j], acc[m][j]);
            }
        }
    }

    __syncthreads();
    #pragma unroll
    for (int j = 0; j < 4; ++j) {
        const float bj = b3[cbase + j * 64];
        #pragma unroll
        for (int m = 0; m < 8; ++m)
            sX[(rbase + m) * HIDDEN + cbase + j * 64] = fmaxf(acc[m][j] + bj, 0.0f);
    }

    const int cb2 = ch * 128 + cg;
    float acc2[8][2] = {};
    for (int kb = 0; kb < HIDDEN; kb += 8) {
        __syncthreads();
        const float4* w4 = reinterpret_cast<const float4*>(W4 + (size_t)kb * NODE_DIM);
        for (int i = tid; i < 512; i += 256) sW4[i] = w4[i];
        __syncthreads();
        #pragma unroll
        for (int kq = 0; kq < 2; ++kq) {
            float4 xq[8];
            #pragma unroll
            for (int m = 0; m < 8; ++m)
                xq[m] = sX4[(rbase + m) * 128 + (kb >> 2) + kq];
            #pragma unroll
            for (int kc = 0; kc < 4; ++kc) {
                const int k = kq * 4 + kc;
                float wv[2];
                #pragma unroll
                for (int j = 0; j < 2; ++j) wv[j] = sW[k * NODE_DIM + cb2 + j * 64];
                #pragma unroll
                for (int m = 0; m < 8; ++m)
                    #pragma unroll
                    for (int j = 0; j < 2; ++j)
                        acc2[m][j] = fmaf(f4c(xq[m], kc), wv[j], acc2[m][j]);
            }
        }
    }

    #pragma unroll
    for (int j = 0; j < 2; ++j) {
        const float bj = b4[cb2 + j * 64];
        #pragma unroll
        for (int m = 0; m < 8; ++m) {
            const size_t o = (size_t)(rb + rbase + m) * NODE_DIM + cb2 + j * 64;
            out[o] = nf[o] + acc2[m][j] + bj;
        }
    }
}

extern "C" void kernel_launch(void* const* d_in, const int* in_sizes, int n_in,
                              void* d_out, int out_size, void* d_ws, size_t ws_size,
                              hipStream_t stream)
{
    const float* nf = (const float*)d_in[0];
    const int*   ei = (const int*)d_in[1];
    const float* ef = (const float*)d_in[2];
    const float* W1 = (const float*)d_in[3];
    const float* b1 = (const float*)d_in[4];
    const float* W2 = (const float*)d_in[5];
    const float* b2 = (const float*)d_in[6];
    const float* W3 = (const float*)d_in[7];
    const float* b3 = (const float*)d_in[8];
    const float* W4 = (const float*)d_in[9];
    const float* b4 = (const float*)d_in[10];
    float* out = (float*)d_out;

    // workspace layout (needs ~44.2 MB):
    //   agg  [20000][512] fp32 @ 0            (40,960,000 B)
    //   w1h/w1l bf16 @ 41,943,040 / +589,824
    //   w2h/w2l bf16 @ 43,122,688 / +524,288
    char* ws = (char*)d_ws;
    float*          agg = (float*)ws;
    unsigned short* w1h = (unsigned short*)(ws + 41943040);
    unsigned short* w1l = (unsigned short*)(ws + 41943040 + 589824);
    unsigned short* w2h = (unsigned short*)(ws + 43122688);
    unsigned short* w2l = (unsigned short*)(ws + 43122688 + 524288);

    const int* src = ei;
    const int* tgt = ei + NUM_EDGES;

    static bool attr_set = false;   // host-side only; same GPU work every call
    (void)hipFuncSetAttribute(reinterpret_cast<const void*>(&edge_mlp_mfma),
                              hipFuncAttributeMaxDynamicSharedMemorySize, 147456);

    hipMemsetAsync(agg, 0, (size_t)NUM_NODES * HIDDEN * sizeof(float), stream);
    prep_weights<<<1088, 256, 0, stream>>>(W1, W2, w1h, w1l, w2h, w2l);
    edge_mlp_mfma<<<NUM_EDGES / 64, 512, 147456, stream>>>(
        nf, src, tgt, ef, w1h, w1l, w2h, w2l, b1, b2, agg);
    node_mlp_kernel<<<NUM_NODES / 16, 256, 0, stream>>>(nf, agg, W3, b3, W4, b4, out);
}

// Round 3
// 933.820 us; speedup vs baseline: 5.6896x; 5.6896x over previous
//
#include <hip/hip_runtime.h>

#define NUM_NODES 20000
#define NUM_EDGES 320000
#define NODE_DIM  256
#define EDGE_DIM  64
#define HIDDEN    512

typedef short  s16x8  __attribute__((ext_vector_type(8)));
typedef float  f32x16 __attribute__((ext_vector_type(16)));
typedef unsigned short us16;

__device__ __forceinline__ us16 f2bf(float f) {
    union { float f; unsigned u; } c; c.f = f;
    unsigned r = c.u + 0x7fffu + ((c.u >> 16) & 1u);   // RNE
    return (us16)(r >> 16);
}
__device__ __forceinline__ float bf2f(us16 b) {
    union { unsigned u; float f; } c; c.u = ((unsigned)b) << 16;
    return c.f;
}
// swap bit2<->bit3: makes the 8 k-elements of an MFMA 32x32x16 A/B fragment
// contiguous in storage (validated on-HW by round-2 PASS).
__device__ __forceinline__ int swapmid(int x) {
    return (x & 3) | ((x & 4) << 1) | ((x & 8) >> 1);
}
__device__ __forceinline__ void zero16(f32x16& a) {
    #pragma unroll
    for (int i = 0; i < 16; ++i) a[i] = 0.0f;
}
__device__ __forceinline__ void mfma3(f32x16& acc, s16x8 ah, s16x8 al, s16x8 bh, s16x8 bl) {
    acc = __builtin_amdgcn_mfma_f32_32x32x16_bf16(ah, bh, acc, 0, 0, 0);
    acc = __builtin_amdgcn_mfma_f32_32x32x16_bf16(ah, bl, acc, 0, 0, 0);
    acc = __builtin_amdgcn_mfma_f32_32x32x16_bf16(al, bh, acc, 0, 0, 0);
}
// hi/lo bf16 split of a float4 into swizzled, k-permuted LDS B-tile (STRIDE bytes/row)
template<int STRIDE>
__device__ __forceinline__ void stash_quad(char* hi, char* lo, int r, int c, float4 v) {
    int cpp = (c & ~15) | swapmid(c & 15);      // c is 4-aligned -> quad stays contiguous
    int off = r * STRIDE + ((cpp * 2) ^ ((r & 7) << 4));
    us16 h0 = f2bf(v.x), h1 = f2bf(v.y), h2 = f2bf(v.z), h3 = f2bf(v.w);
    uint2 uh; uh.x = h0 | ((unsigned)h1 << 16); uh.y = h2 | ((unsigned)h3 << 16);
    uint2 ul;
    ul.x = f2bf(v.x - bf2f(h0)) | ((unsigned)f2bf(v.y - bf2f(h1)) << 16);
    ul.y = f2bf(v.z - bf2f(h2)) | ((unsigned)f2bf(v.w - bf2f(h3)) << 16);
    *reinterpret_cast<uint2*>(hi + off) = uh;
    *reinterpret_cast<uint2*>(lo + off) = ul;
}
template<int STRIDE>
__device__ __forceinline__ void bread(const char* hi, const char* lo, int r, int kbyte,
                                      s16x8& bh, s16x8& bl) {
    int off = r * STRIDE + (kbyte ^ ((r & 7) << 4));
    bh = *reinterpret_cast<const s16x8*>(hi + off);
    bl = *reinterpret_cast<const s16x8*>(lo + off);
}

// ---------------- CSR build ----------------
__global__ void build_deg(const int* __restrict__ tgt, int* __restrict__ deg) {
    int i = blockIdx.x * 256 + threadIdx.x;
    if (i < NUM_EDGES) atomicAdd(&deg[tgt[i]], 1);
}

__global__ void scan_deg(const int* __restrict__ deg, int* __restrict__ off) {
    __shared__ int buf[1024];
    __shared__ int carry;
    int tid = threadIdx.x;
    if (tid == 0) { carry = 0; off[0] = 0; }
    __syncthreads();
    for (int base = 0; base < NUM_NODES; base += 1024) {
        int v = (base + tid < NUM_NODES) ? deg[base + tid] : 0;
        buf[tid] = v; __syncthreads();
        for (int d = 1; d < 1024; d <<= 1) {
            int add = (tid >= d) ? buf[tid - d] : 0;
            __syncthreads();
            buf[tid] += add;
            __syncthreads();
        }
        int inc = buf[tid] + carry;
        if (base + tid < NUM_NODES) off[base + tid + 1] = inc;
        __syncthreads();
        if (tid == 1023) carry = inc;
        __syncthreads();
    }
}

__global__ void fill_csr(const int* __restrict__ tgt, const int* __restrict__ off,
                         int* __restrict__ cursor, int* __restrict__ csr) {
    int i = blockIdx.x * 256 + threadIdx.x;
    if (i < NUM_EDGES) {
        int t = tgt[i];
        int p = atomicAdd(&cursor[t], 1);
        csr[off[t] + p] = i;
    }
}

// ---------------- W23 = W2 @ W3b, b23 = b2 @ W3b (fp32) ----------------
__global__ void compute_w23(const float* __restrict__ W2, const float* __restrict__ b2,
                            const float* __restrict__ W3,
                            float* __restrict__ W23, float* __restrict__ b23) {
    int n = blockIdx.y * 256 + threadIdx.x;
    int i = blockIdx.x;
    const float* w3b = W3 + 256 * 512 + n;     // W3 rows 256.., stride 512
    float s = 0.f;
    if (i < 512) {
        const float* w2r = W2 + i * 512;
        for (int j = 0; j < 512; ++j) s = fmaf(w2r[j], w3b[(size_t)j * 512], s);
        W23[i * 512 + n] = s;
    } else {
        for (int j = 0; j < 512; ++j) s = fmaf(b2[j], w3b[(size_t)j * 512], s);
        b23[n] = s;
    }
}

// ---------------- weight planes: fp32 [K][N] -> bf16 hi/lo [kb][N][16perm] ----------------
__global__ void prep_planes(const float* __restrict__ W1, const float* __restrict__ W3,
                            const float* __restrict__ W4, const float* __restrict__ W23,
                            us16* __restrict__ wab_h, us16* __restrict__ wab_l,
                            us16* __restrict__ wc_h,  us16* __restrict__ wc_l,
                            us16* __restrict__ w34_h, us16* __restrict__ w34_l,
                            us16* __restrict__ w4_h,  us16* __restrict__ w4_l) {
    int idx = blockIdx.x * 256 + threadIdx.x;   // total 819200
    float w; us16 *dh, *dl; int k, n, N;
    if (idx < 262144) {                          // W1ab^T: K=256, N=1024
        n = idx & 1023; k = idx >> 10; N = 1024;
        w = W1[(k + (n >= 512 ? 256 : 0)) * 512 + (n & 511)];
        dh = wab_h; dl = wab_l;
    } else if (idx < 294912) {                   // W1c^T: K=64, N=512
        int j = idx - 262144; n = j & 511; k = j >> 9; N = 512;
        w = W1[(512 + k) * 512 + n];
        dh = wc_h; dl = wc_l;
    } else if (idx < 688128) {                   // [W3a; W23]^T: K=768, N=512
        int j = idx - 294912; n = j & 511; k = j >> 9; N = 512;
        w = (k < 256) ? W3[k * 512 + n] : W23[(k - 256) * 512 + n];
        dh = w34_h; dl = w34_l;
    } else {                                     // W4^T: K=512, N=256
        int j = idx - 688128; n = j & 255; k = j >> 8; N = 256;
        w = W4[k * 256 + n];
        dh = w4_h; dl = w4_l;
    }
    us16 h = f2bf(w);
    us16 l = f2bf(w - bf2f(h));
    int d = (k >> 4) * (N * 16) + n * 16 + swapmid(k & 15);
    dh[d] = h; dl[d] = l;
}

// ---------------- P = nf @ [W1a | W1b]  (20000 x 1024) ----------------
__global__ __launch_bounds__(512, 2)
void gemm_p(const float* __restrict__ nf,
            const us16* __restrict__ wab_h, const us16* __restrict__ wab_l,
            float* __restrict__ P) {
    __shared__ char sB[32768];                   // 32 rows x 512B, hi @0 / lo @16384
    const int tid = threadIdx.x;
    const int nb  = blockIdx.x * 32;
    const int half = blockIdx.y;

    const float4* nf4 = reinterpret_cast<const float4*>(nf);
    for (int i = tid; i < 32 * 64; i += 512) {
        int r = i >> 6, q = i & 63;
        stash_quad<512>(sB, sB + 16384, r, 4 * q, nf4[(size_t)(nb + r) * 64 + q]);
    }
    __syncthreads();

    const int w = tid >> 6, l = tid & 63, le = l & 31, g = l >> 5;
    const s16x8* Ah = reinterpret_cast<const s16x8*>(wab_h);
    const s16x8* Al = reinterpret_cast<const s16x8*>(wab_l);
    const int nbase = half * 512 + w * 64;

    f32x16 acc[2]; zero16(acc[0]); zero16(acc[1]);
    for (int ks = 0; ks < 16; ++ks) {
        s16x8 AH[2], AL[2], bh, bl;
        #pragma unroll
        for (int mt = 0; mt < 2; ++mt) {
            int idx = ks * 2048 + (nbase + 32 * mt + le) * 2 + g;   // N=1024
            AH[mt] = Ah[idx]; AL[mt] = Al[idx];
        }
        bread<512>(sB, sB + 16384, le, ks * 32 + 16 * g, bh, bl);
        #pragma unroll
        for (int mt = 0; mt < 2; ++mt) mfma3(acc[mt], AH[mt], AL[mt], bh, bl);
    }

    float4* P4 = reinterpret_cast<float4*>(P);
    #pragma unroll
    for (int mt = 0; mt < 2; ++mt)
        #pragma unroll
        for (int rq = 0; rq < 4; ++rq) {
            int nn = nbase + 32 * mt + 4 * g + 8 * rq;
            float4 o = make_float4(acc[mt][4*rq+0], acc[mt][4*rq+1],
                                   acc[mt][4*rq+2], acc[mt][4*rq+3]);
            P4[(size_t)(nb + le) * 256 + (nn >> 2)] = o;
        }
}

// ---------------- edge kernel: h = relu(P_s[src]+P_t[tgt]+ef@W1c+b1), seg-reduce, atomic ----------------
__global__ __launch_bounds__(512, 2)
void edge_csr(const float* __restrict__ ef,
              const int* __restrict__ srcI, const int* __restrict__ tgtI,
              const int* __restrict__ csr,
              const us16* __restrict__ wc_h, const us16* __restrict__ wc_l,
              const float* __restrict__ b1, const float* __restrict__ P,
              float* __restrict__ aggH) {
    __shared__ char sB[16384];                   // ef tile: 64 rows x 128B, hi @0 / lo @8192
    __shared__ int sEid[64], sSrc[64], sTgt[64];

    const int tid  = threadIdx.x;
    const int orig = blockIdx.x;
    const int wg   = (orig & 7) * 625 + (orig >> 3);   // chunked XCD swizzle (5000 = 8*625)
    const int cb   = wg * 64;

    if (tid < 64) {
        int eid = csr[cb + tid];
        sEid[tid] = eid; sSrc[tid] = srcI[eid]; sTgt[tid] = tgtI[eid];
    }
    __syncthreads();

    const float4* ef4 = reinterpret_cast<const float4*>(ef);
    for (int i = tid; i < 64 * 16; i += 512) {
        int e = i >> 4, q = i & 15;
        stash_quad<128>(sB, sB + 8192, e, 4 * q, ef4[(size_t)sEid[e] * 16 + q]);
    }
    __syncthreads();

    const int w = tid >> 6, l = tid & 63, le = l & 31, g = l >> 5;
    const s16x8* Ah = reinterpret_cast<const s16x8*>(wc_h);
    const s16x8* Al = reinterpret_cast<const s16x8*>(wc_l);

    f32x16 acc[2][2];
    #pragma unroll
    for (int mt = 0; mt < 2; ++mt) { zero16(acc[mt][0]); zero16(acc[mt][1]); }

    for (int ks = 0; ks < 4; ++ks) {
        s16x8 AH[2], AL[2], bh[2], bl[2];
        #pragma unroll
        for (int mt = 0; mt < 2; ++mt) {
            int idx = ks * 1024 + (w * 64 + 32 * mt + le) * 2 + g;   // N=512
            AH[mt] = Ah[idx]; AL[mt] = Al[idx];
        }
        #pragma unroll
        for (int nt = 0; nt < 2; ++nt)
            bread<128>(sB, sB + 8192, 32 * nt + le, ks * 32 + 16 * g, bh[nt], bl[nt]);
        #pragma unroll
        for (int mt = 0; mt < 2; ++mt)
            #pragma unroll
            for (int nt = 0; nt < 2; ++nt)
                mfma3(acc[mt][nt], AH[mt], AL[mt], bh[nt], bl[nt]);
    }

    const float4* P4  = reinterpret_cast<const float4*>(P);
    const float4* b14 = reinterpret_cast<const float4*>(b1);

    #pragma unroll
    for (int nt = 0; nt < 2; ++nt) {
        const int es = 32 * nt + le;
        const int t = sTgt[es], s = sSrc[es];
        int tp = __shfl_up(t, 1, 32);
        const bool head = (le == 0) || (tp != t);
        bool eq[5];
        #pragma unroll
        for (int d = 0; d < 5; ++d) {
            int td = __shfl_down(t, 1 << d, 32);
            eq[d] = (le + (1 << d) < 32) && (td == t);
        }
        #pragma unroll
        for (int mt = 0; mt < 2; ++mt) {
            float4 ps[4], pt[4];
            #pragma unroll
            for (int rq = 0; rq < 4; ++rq) {
                const int h0 = w * 64 + 32 * mt + 4 * g + 8 * rq;
                ps[rq] = P4[(size_t)s * 256 + (h0 >> 2)];
                pt[rq] = P4[(size_t)t * 256 + 128 + (h0 >> 2)];
            }
            #pragma unroll
            for (int rq = 0; rq < 4; ++rq) {
                const int h0 = w * 64 + 32 * mt + 4 * g + 8 * rq;
                float4 bq = b14[h0 >> 2];
                float v0 = fmaxf(acc[mt][nt][4*rq+0] + ps[rq].x + pt[rq].x + bq.x, 0.f);
                float v1 = fmaxf(acc[mt][nt][4*rq+1] + ps[rq].y + pt[rq].y + bq.y, 0.f);
                float v2 = fmaxf(acc[mt][nt][4*rq+2] + ps[rq].z + pt[rq].z + bq.z, 0.f);
                float v3 = fmaxf(acc[mt][nt][4*rq+3] + ps[rq].w + pt[rq].w + bq.w, 0.f);
                #pragma unroll
                for (int d = 0; d < 5; ++d) {
                    float o0 = __shfl_down(v0, 1 << d, 32);
                    float o1 = __shfl_down(v1, 1 << d, 32);
                    float o2 = __shfl_down(v2, 1 << d, 32);
                    float o3 = __shfl_down(v3, 1 << d, 32);
                    if (eq[d]) { v0 += o0; v1 += o1; v2 += o2; v3 += o3; }
                }
                if (head) {
                    float* dst = aggH + (size_t)t * 512 + h0;
                    atomicAdd(dst + 0, v0); atomicAdd(dst + 1, v1);
                    atomicAdd(dst + 2, v2); atomicAdd(dst + 3, v3);
                }
            }
        }
    }
}

// ---------------- node kernel: out = nf + relu([nf|aggH]@[W3a;W23] + b3 + deg*b23) @ W4 + b4 ----------------
__global__ __launch_bounds__(512, 1)
void node_mlp(const float* __restrict__ nf, const float* __restrict__ aggH,
              const int* __restrict__ deg,
              const us16* __restrict__ w34_h, const us16* __restrict__ w34_l,
              const us16* __restrict__ w4_h,  const us16* __restrict__ w4_l,
              const float* __restrict__ b3, const float* __restrict__ b23,
              const float* __restrict__ b4, float* __restrict__ out) {
    extern __shared__ char sm[];                 // B: 32 x 1536B, hi @0 / lo @49152 (98304 total)
    __shared__ int sDeg[32];
    const int tid = threadIdx.x;
    const int nb  = blockIdx.x * 32;

    if (tid < 32) sDeg[tid] = deg[nb + tid];

    const float4* nf4 = reinterpret_cast<const float4*>(nf);
    const float4* ag4 = reinterpret_cast<const float4*>(aggH);
    for (int i = tid; i < 32 * 64; i += 512) {   // nf -> cols 0..255
        int r = i >> 6, q = i & 63;
        stash_quad<1536>(sm, sm + 49152, r, 4 * q, nf4[(size_t)(nb + r) * 64 + q]);
    }
    for (int i = tid; i < 32 * 128; i += 512) {  // aggH -> cols 256..767
        int r = i >> 7, q = i & 127;
        stash_quad<1536>(sm, sm + 49152, r, 256 + 4 * q, ag4[(size_t)(nb + r) * 128 + q]);
    }
    __syncthreads();

    const int w = tid >> 6, l = tid & 63, le = l & 31, g = l >> 5;

    // layer 3: K=768
    f32x16 acc[2]; zero16(acc[0]); zero16(acc[1]);
    {
        const s16x8* Ah = reinterpret_cast<const s16x8*>(w34_h);
        const s16x8* Al = reinterpret_cast<const s16x8*>(w34_l);
        for (int ks = 0; ks < 48; ++ks) {
            s16x8 AH[2], AL[2], bh, bl;
            #pragma unroll
            for (int mt = 0; mt < 2; ++mt) {
                int idx = ks * 1024 + (w * 64 + 32 * mt + le) * 2 + g;   // N=512
                AH[mt] = Ah[idx]; AL[mt] = Al[idx];
            }
            bread<1536>(sm, sm + 49152, le, ks * 32 + 16 * g, bh, bl);
            #pragma unroll
            for (int mt = 0; mt < 2; ++mt) mfma3(acc[mt], AH[mt], AL[mt], bh, bl);
        }
    }
    __syncthreads();   // done reading B; overlay H tile (32 x 1024B, hi @0 / lo @32768)

    {
        const float4* b34  = reinterpret_cast<const float4*>(b3);
        const float4* b234 = reinterpret_cast<const float4*>(b23);
        const float degv = (float)sDeg[le];      // this lane's node = nb + le
        #pragma unroll
        for (int mt = 0; mt < 2; ++mt)
            #pragma unroll
            for (int rq = 0; rq < 4; ++rq) {
                int hcol = w * 64 + 32 * mt + 4 * g + 8 * rq;
                float4 bq = b34[hcol >> 2], cq = b234[hcol >> 2];
                float4 gv;
                gv.x = fmaxf(acc[mt][4*rq+0] + bq.x + degv * cq.x, 0.f);
                gv.y = fmaxf(acc[mt][4*rq+1] + bq.y + degv * cq.y, 0.f);
                gv.z = fmaxf(acc[mt][4*rq+2] + bq.z + degv * cq.z, 0.f);
                gv.w = fmaxf(acc[mt][4*rq+3] + bq.w + degv * cq.w, 0.f);
                stash_quad<1024>(sm, sm + 32768, le, hcol, gv);
            }
    }
    __syncthreads();

    // layer 4: K=512, N=256 (one 32-col slice per wave)
    f32x16 a2; zero16(a2);
    {
        const s16x8* Ah = reinterpret_cast<const s16x8*>(w4_h);
        const s16x8* Al = reinterpret_cast<const s16x8*>(w4_l);
        for (int ks = 0; ks < 32; ++ks) {
            s16x8 AH, AL, bh, bl;
            int idx = ks * 512 + (w * 32 + le) * 2 + g;   // N=256
            AH = Ah[idx]; AL = Al[idx];
            bread<1024>(sm, sm + 32768, le, ks * 32 + 16 * g, bh, bl);
            mfma3(a2, AH, AL, bh, bl);
        }
    }

    const float4* b44 = reinterpret_cast<const float4*>(b4);
    float4* out4 = reinterpret_cast<float4*>(out);
    #pragma unroll
    for (int rq = 0; rq < 4; ++rq) {
        int n0 = w * 32 + 4 * g + 8 * rq;
        float4 bq  = b44[n0 >> 2];
        float4 res = nf4[(size_t)(nb + le) * 64 + (n0 >> 2)];
        float4 o;
        o.x = res.x + a2[4*rq+0] + bq.x;
        o.y = res.y + a2[4*rq+1] + bq.y;
        o.z = res.z + a2[4*rq+2] + bq.z;
        o.w = res.w + a2[4*rq+3] + bq.w;
        out4[(size_t)(nb + le) * 64 + (n0 >> 2)] = o;
    }
}

extern "C" void kernel_launch(void* const* d_in, const int* in_sizes, int n_in,
                              void* d_out, int out_size, void* d_ws, size_t ws_size,
                              hipStream_t stream) {
    const float* nf = (const float*)d_in[0];
    const int*   ei = (const int*)d_in[1];
    const float* ef = (const float*)d_in[2];
    const float* W1 = (const float*)d_in[3];
    const float* b1 = (const float*)d_in[4];
    const float* W2 = (const float*)d_in[5];
    const float* b2 = (const float*)d_in[6];
    const float* W3 = (const float*)d_in[7];
    const float* b3 = (const float*)d_in[8];
    const float* W4 = (const float*)d_in[9];
    const float* b4 = (const float*)d_in[10];
    float* out = (float*)d_out;

    // workspace layout (total 128,727,440 B)
    char* ws = (char*)d_ws;
    float* P      = (float*)(ws + 0);               // 20000x1024 fp32
    float* aggH   = (float*)(ws + 81920000);        // 20000x512  fp32
    us16*  wab_h  = (us16*)(ws + 122880000);
    us16*  wab_l  = (us16*)(ws + 123404288);
    us16*  wc_h   = (us16*)(ws + 123928576);
    us16*  wc_l   = (us16*)(ws + 123994112);
    us16*  w34_h  = (us16*)(ws + 124059648);
    us16*  w34_l  = (us16*)(ws + 124846080);
    us16*  w4_h   = (us16*)(ws + 125632512);
    us16*  w4_l   = (us16*)(ws + 125894656);
    float* W23    = (float*)(ws + 126156800);       // 512x512 fp32
    float* b23    = (float*)(ws + 127205376);       // 512 fp32
    int*   deg    = (int*)  (ws + 127207424);       // 20000
    int*   cursor = (int*)  (ws + 127287424);       // 20000
    int*   offs   = (int*)  (ws + 127367424);       // 20001
    int*   csr    = (int*)  (ws + 127447440);       // 320000

    const int* src = ei;                 // edge_index[0]
    const int* tgt = ei + NUM_EDGES;     // edge_index[1]

    (void)hipFuncSetAttribute(reinterpret_cast<const void*>(&node_mlp),
                              hipFuncAttributeMaxDynamicSharedMemorySize, 98304);

    hipMemsetAsync(deg, 0, 160000, stream);                       // deg + cursor
    hipMemsetAsync(aggH, 0, (size_t)NUM_NODES * HIDDEN * 4, stream);

    build_deg<<<1250, 256, 0, stream>>>(tgt, deg);
    scan_deg<<<1, 1024, 0, stream>>>(deg, offs);
    fill_csr<<<1250, 256, 0, stream>>>(tgt, offs, cursor, csr);

    compute_w23<<<dim3(513, 2), 256, 0, stream>>>(W2, b2, W3, W23, b23);
    prep_planes<<<3200, 256, 0, stream>>>(W1, W3, W4, W23,
                                          wab_h, wab_l, wc_h, wc_l,
                                          w34_h, w34_l, w4_h, w4_l);

    gemm_p<<<dim3(625, 2), 512, 0, stream>>>(nf, wab_h, wab_l, P);
    edge_csr<<<5000, 512, 0, stream>>>(ef, src, tgt, csr, wc_h, wc_l, b1, P, aggH);
    node_mlp<<<625, 512, 98304, stream>>>(nf, aggH, deg, w34_h, w34_l,
                                          w4_h, w4_l, b3, b23, b4, out);
}

// Round 4
// 821.610 us; speedup vs baseline: 6.4667x; 1.1366x over previous
//
#include <hip/hip_runtime.h>

#define NUM_NODES 20000
#define NUM_EDGES 320000
#define NODE_DIM  256
#define EDGE_DIM  64
#define HIDDEN    512

typedef short  s16x8  __attribute__((ext_vector_type(8)));
typedef float  f32x16 __attribute__((ext_vector_type(16)));
typedef unsigned short us16;

__device__ __forceinline__ us16 f2bf(float f) {
    union { float f; unsigned u; } c; c.f = f;
    unsigned r = c.u + 0x7fffu + ((c.u >> 16) & 1u);   // RNE
    return (us16)(r >> 16);
}
__device__ __forceinline__ float bf2f(us16 b) {
    union { unsigned u; float f; } c; c.u = ((unsigned)b) << 16;
    return c.f;
}
// swap bit2<->bit3: makes the 8 k-elements of an MFMA 32x32x16 A/B fragment
// contiguous in storage (HW-validated by round-2/3 PASS).
__device__ __forceinline__ int swapmid(int x) {
    return (x & 3) | ((x & 4) << 1) | ((x & 8) >> 1);
}
__device__ __forceinline__ void zero16(f32x16& a) {
    #pragma unroll
    for (int i = 0; i < 16; ++i) a[i] = 0.0f;
}
__device__ __forceinline__ void mfma3(f32x16& acc, s16x8 ah, s16x8 al, s16x8 bh, s16x8 bl) {
    acc = __builtin_amdgcn_mfma_f32_32x32x16_bf16(ah, bh, acc, 0, 0, 0);
    acc = __builtin_amdgcn_mfma_f32_32x32x16_bf16(ah, bl, acc, 0, 0, 0);
    acc = __builtin_amdgcn_mfma_f32_32x32x16_bf16(al, bh, acc, 0, 0, 0);
}
template<int STRIDE>
__device__ __forceinline__ void stash_quad(char* hi, char* lo, int r, int c, float4 v) {
    int cpp = (c & ~15) | swapmid(c & 15);      // c is 4-aligned -> quad stays contiguous
    int off = r * STRIDE + ((cpp * 2) ^ ((r & 7) << 4));
    us16 h0 = f2bf(v.x), h1 = f2bf(v.y), h2 = f2bf(v.z), h3 = f2bf(v.w);
    uint2 uh; uh.x = h0 | ((unsigned)h1 << 16); uh.y = h2 | ((unsigned)h3 << 16);
    uint2 ul;
    ul.x = f2bf(v.x - bf2f(h0)) | ((unsigned)f2bf(v.y - bf2f(h1)) << 16);
    ul.y = f2bf(v.z - bf2f(h2)) | ((unsigned)f2bf(v.w - bf2f(h3)) << 16);
    *reinterpret_cast<uint2*>(hi + off) = uh;
    *reinterpret_cast<uint2*>(lo + off) = ul;
}
template<int STRIDE>
__device__ __forceinline__ void bread(const char* hi, const char* lo, int r, int kbyte,
                                      s16x8& bh, s16x8& bl) {
    int off = r * STRIDE + (kbyte ^ ((r & 7) << 4));
    bh = *reinterpret_cast<const s16x8*>(hi + off);
    bl = *reinterpret_cast<const s16x8*>(lo + off);
}

// ---------------- CSR build ----------------
__global__ void build_deg(const int* __restrict__ tgt, int* __restrict__ deg) {
    int i = blockIdx.x * 256 + threadIdx.x;
    if (i < NUM_EDGES) atomicAdd(&deg[tgt[i]], 1);
}

__global__ void scan_deg(const int* __restrict__ deg, int* __restrict__ off) {
    __shared__ int buf[1024];
    __shared__ int carry;
    int tid = threadIdx.x;
    if (tid == 0) { carry = 0; off[0] = 0; }
    __syncthreads();
    for (int base = 0; base < NUM_NODES; base += 1024) {
        int v = (base + tid < NUM_NODES) ? deg[base + tid] : 0;
        buf[tid] = v; __syncthreads();
        for (int d = 1; d < 1024; d <<= 1) {
            int add = (tid >= d) ? buf[tid - d] : 0;
            __syncthreads();
            buf[tid] += add;
            __syncthreads();
        }
        int inc = buf[tid] + carry;
        if (base + tid < NUM_NODES) off[base + tid + 1] = inc;
        __syncthreads();
        if (tid == 1023) carry = inc;
        __syncthreads();
    }
}

__global__ void fill_csr(const int* __restrict__ tgt, const int* __restrict__ off,
                         int* __restrict__ cursor, int* __restrict__ csr) {
    int i = blockIdx.x * 256 + threadIdx.x;
    if (i < NUM_EDGES) {
        int t = tgt[i];
        int p = atomicAdd(&cursor[t], 1);
        csr[off[t] + p] = i;
    }
}

// ---------------- W23 = W2 @ W3b, b23 = b2 @ W3b (fp32) ----------------
__global__ void compute_w23(const float* __restrict__ W2, const float* __restrict__ b2,
                            const float* __restrict__ W3,
                            float* __restrict__ W23, float* __restrict__ b23) {
    int n = blockIdx.y * 256 + threadIdx.x;
    int i = blockIdx.x;
    const float* w3b = W3 + 256 * 512 + n;     // W3 rows 256.., stride 512
    float s = 0.f;
    if (i < 512) {
        const float* w2r = W2 + i * 512;
        for (int j = 0; j < 512; ++j) s = fmaf(w2r[j], w3b[(size_t)j * 512], s);
        W23[i * 512 + n] = s;
    } else {
        for (int j = 0; j < 512; ++j) s = fmaf(b2[j], w3b[(size_t)j * 512], s);
        b23[n] = s;
    }
}

// ---------------- weight planes: fp32 [K][N] -> bf16 hi/lo [kb][N][16perm] ----------------
__global__ void prep_planes(const float* __restrict__ W1, const float* __restrict__ W3,
                            const float* __restrict__ W4, const float* __restrict__ W23,
                            us16* __restrict__ wab_h, us16* __restrict__ wab_l,
                            us16* __restrict__ wc_h,  us16* __restrict__ wc_l,
                            us16* __restrict__ w34_h, us16* __restrict__ w34_l,
                            us16* __restrict__ w4_h,  us16* __restrict__ w4_l) {
    int idx = blockIdx.x * 256 + threadIdx.x;   // total 819200
    float w; us16 *dh, *dl; int k, n, N;
    if (idx < 262144) {                          // W1ab^T: K=256, N=1024
        n = idx & 1023; k = idx >> 10; N = 1024;
        w = W1[(k + (n >= 512 ? 256 : 0)) * 512 + (n & 511)];
        dh = wab_h; dl = wab_l;
    } else if (idx < 294912) {                   // W1c^T: K=64, N=512
        int j = idx - 262144; n = j & 511; k = j >> 9; N = 512;
        w = W1[(512 + k) * 512 + n];
        dh = wc_h; dl = wc_l;
    } else if (idx < 688128) {                   // [W3a; W23]^T: K=768, N=512
        int j = idx - 294912; n = j & 511; k = j >> 9; N = 512;
        w = (k < 256) ? W3[k * 512 + n] : W23[(k - 256) * 512 + n];
        dh = w34_h; dl = w34_l;
    } else {                                     // W4^T: K=512, N=256
        int j = idx - 688128; n = j & 255; k = j >> 8; N = 256;
        w = W4[k * 256 + n];
        dh = w4_h; dl = w4_l;
    }
    us16 h = f2bf(w);
    us16 l = f2bf(w - bf2f(h));
    int d = (k >> 4) * (N * 16) + n * 16 + swapmid(k & 15);
    dh[d] = h; dl[d] = l;
}

// ---------------- P = nf @ [W1a | W1b]  (20000 x 1024), 64-row tiles ----------------
__global__ __launch_bounds__(512, 2)
void gemm_p(const float* __restrict__ nf,
            const us16* __restrict__ wab_h, const us16* __restrict__ wab_l,
            float* __restrict__ P) {
    extern __shared__ char sB[];                 // 64 rows x 512B, hi @0 / lo @32768
    const int tid = threadIdx.x;
    const int nb  = blockIdx.x * 64;
    const int half = blockIdx.y;

    const float4* nf4 = reinterpret_cast<const float4*>(nf);
    for (int i = tid; i < 64 * 64; i += 512) {
        int r = i >> 6, q = i & 63;
        int row = nb + r; if (row >= NUM_NODES) row = NUM_NODES - 1;
        stash_quad<512>(sB, sB + 32768, r, 4 * q, nf4[(size_t)row * 64 + q]);
    }
    __syncthreads();

    const int w = tid >> 6, l = tid & 63, le = l & 31, g = l >> 5;
    const s16x8* Ah = reinterpret_cast<const s16x8*>(wab_h);
    const s16x8* Al = reinterpret_cast<const s16x8*>(wab_l);
    const int nbase = half * 512 + w * 64;

    f32x16 acc[2][2];                            // [mt][row-tile]
    #pragma unroll
    for (int a = 0; a < 2; ++a) { zero16(acc[a][0]); zero16(acc[a][1]); }

    for (int ks = 0; ks < 16; ++ks) {
        s16x8 AH[2], AL[2], bh[2], bl[2];
        #pragma unroll
        for (int mt = 0; mt < 2; ++mt) {
            int idx = ks * 2048 + (nbase + 32 * mt + le) * 2 + g;   // N=1024
            AH[mt] = Ah[idx]; AL[mt] = Al[idx];
        }
        #pragma unroll
        for (int rt = 0; rt < 2; ++rt)
            bread<512>(sB, sB + 32768, 32 * rt + le, ks * 32 + 16 * g, bh[rt], bl[rt]);
        #pragma unroll
        for (int mt = 0; mt < 2; ++mt)
            #pragma unroll
            for (int rt = 0; rt < 2; ++rt)
                mfma3(acc[mt][rt], AH[mt], AL[mt], bh[rt], bl[rt]);
    }

    float4* P4 = reinterpret_cast<float4*>(P);
    #pragma unroll
    for (int rt = 0; rt < 2; ++rt) {
        int row = nb + 32 * rt + le;
        if (row < NUM_NODES) {
            #pragma unroll
            for (int mt = 0; mt < 2; ++mt)
                #pragma unroll
                for (int rq = 0; rq < 4; ++rq) {
                    int nn = nbase + 32 * mt + 4 * g + 8 * rq;
                    float4 o = make_float4(acc[mt][rt][4*rq+0], acc[mt][rt][4*rq+1],
                                           acc[mt][rt][4*rq+2], acc[mt][rt][4*rq+3]);
                    P4[(size_t)row * 256 + (nn >> 2)] = o;
                }
        }
    }
}

// ---------------- edge kernel v2: C in LDS, coalesced P gather, sequential reduce ----------------
__global__ __launch_bounds__(512, 2)
void edge_csr(const int* __restrict__ srcI, const int* __restrict__ tgtI,
              const int* __restrict__ csr, const float* __restrict__ ef,
              const us16* __restrict__ wc_h, const us16* __restrict__ wc_l,
              const float* __restrict__ b1, const float* __restrict__ P,
              float* __restrict__ aggH) {
    extern __shared__ char dsm[];                // sC fp32 32x512 @0 (65536), ef tile @65536 (8192)
    char* sC = dsm;
    char* sB = dsm + 65536;
    __shared__ int sEid[64], sSrc[64], sTgt[64];

    const int tid  = threadIdx.x;
    const int orig = blockIdx.x;
    const int wg   = (orig & 7) * 625 + (orig >> 3);   // chunked XCD swizzle (5000 = 8*625)
    const int cb   = wg * 64;

    if (tid < 64) {
        int eid = csr[cb + tid];
        sEid[tid] = eid; sSrc[tid] = srcI[eid]; sTgt[tid] = tgtI[eid];
    }
    __syncthreads();

    const float4* ef4 = reinterpret_cast<const float4*>(ef);
    const float4* P4  = reinterpret_cast<const float4*>(P);
    const float4* b14 = reinterpret_cast<const float4*>(b1);
    const int w = tid >> 6, l = tid & 63, le = l & 31, g = l >> 5;
    const s16x8* Ah = reinterpret_cast<const s16x8*>(wc_h);
    const s16x8* Al = reinterpret_cast<const s16x8*>(wc_l);

    #pragma unroll
    for (int half = 0; half < 2; ++half) {
        {   // stage ef half-tile: exactly one quad per thread (32 edges x 16 quads)
            int e = tid >> 4, q = tid & 15;
            stash_quad<128>(sB, sB + 4096, e, 4 * q,
                            ef4[(size_t)sEid[half * 32 + e] * 16 + q]);
        }
        __syncthreads();

        // MFMA: C = ef @ W1c + b1 for this wave's 64 cols, 32 edges -> LDS
        #pragma unroll
        for (int mt = 0; mt < 2; ++mt) {
            f32x16 acc; zero16(acc);
            #pragma unroll
            for (int ks = 0; ks < 4; ++ks) {
                int idx = ks * 1024 + (w * 64 + 32 * mt + le) * 2 + g;   // N=512
                s16x8 bh, bl;
                bread<128>(sB, sB + 4096, le, ks * 32 + 16 * g, bh, bl);
                mfma3(acc, Ah[idx], Al[idx], bh, bl);
            }
            #pragma unroll
            for (int rq = 0; rq < 4; ++rq) {
                int h0 = w * 64 + 32 * mt + 4 * g + 8 * rq;
                float4 bq = b14[h0 >> 2];
                float4 v = make_float4(acc[4*rq+0] + bq.x, acc[4*rq+1] + bq.y,
                                       acc[4*rq+2] + bq.z, acc[4*rq+3] + bq.w);
                *reinterpret_cast<float4*>(sC + le * 2048 + ((h0 * 4) ^ ((le & 15) << 4))) = v;
            }
        }
        __syncthreads();

        {   // reduce: 128-thread groups sweep full rows (coalesced); sequential 8-edge walk
            const int slice = tid & 127;             // quad 0..127 of the 512-col row
            const int e0    = half * 32 + (tid >> 7) * 8;
            float4 sum = make_float4(0.f, 0.f, 0.f, 0.f);
            int tcur = sTgt[e0];
            float4 pt = P4[(size_t)tcur * 256 + 128 + slice];
            #pragma unroll
            for (int i = 0; i < 8; ++i) {
                int eg = e0 + i;
                int t = sTgt[eg];                    // uniform across the 128-thread group
                if (t != tcur) {
                    float* d = aggH + (size_t)tcur * 512 + slice * 4;
                    atomicAdd(d + 0, sum.x); atomicAdd(d + 1, sum.y);
                    atomicAdd(d + 2, sum.z); atomicAdd(d + 3, sum.w);
                    sum = make_float4(0.f, 0.f, 0.f, 0.f);
                    tcur = t;
                    pt = P4[(size_t)t * 256 + 128 + slice];
                }
                float4 pa = P4[(size_t)sSrc[eg] * 256 + slice];   // coalesced row read
                int crow = eg & 31;
                float4 c = *reinterpret_cast<const float4*>(
                    sC + crow * 2048 + ((slice * 16) ^ ((crow & 15) << 4)));
                sum.x += fmaxf(pa.x + pt.x + c.x, 0.f);
                sum.y += fmaxf(pa.y + pt.y + c.y, 0.f);
                sum.z += fmaxf(pa.z + pt.z + c.z, 0.f);
                sum.w += fmaxf(pa.w + pt.w + c.w, 0.f);
            }
            float* d = aggH + (size_t)tcur * 512 + slice * 4;
            atomicAdd(d + 0, sum.x); atomicAdd(d + 1, sum.y);
            atomicAdd(d + 2, sum.z); atomicAdd(d + 3, sum.w);
        }
        __syncthreads();
    }
}

// ---------------- node kernel: K-chunked double-buffered staging ----------------
__global__ __launch_bounds__(512, 2)
void node_mlp(const float* __restrict__ nf, const float* __restrict__ aggH,
              const int* __restrict__ deg,
              const us16* __restrict__ w34_h, const us16* __restrict__ w34_l,
              const us16* __restrict__ w4_h,  const us16* __restrict__ w4_l,
              const float* __restrict__ b3, const float* __restrict__ b23,
              const float* __restrict__ b4, float* __restrict__ out) {
    extern __shared__ char sm[];                 // buf0 @0, buf1 @32768 (each 32x256k hi/lo)
    __shared__ int sDeg[32];                     // H overlays @0..65536 after layer 3
    const int tid = threadIdx.x;
    const int nb  = blockIdx.x * 32;

    if (tid < 32) sDeg[tid] = deg[nb + tid];

    const float4* nf4 = reinterpret_cast<const float4*>(nf);
    const float4* ag4 = reinterpret_cast<const float4*>(aggH);
    auto stage = [&](int c, char* buf) {         // chunk c: k in [256c, 256c+256)
        for (int i = tid; i < 32 * 64; i += 512) {
            int r = i >> 6, q = i & 63;
            float4 v = (c == 0) ? nf4[(size_t)(nb + r) * 64 + q]
                                : ag4[(size_t)(nb + r) * 128 + (c - 1) * 64 + q];
            stash_quad<512>(buf, buf + 16384, r, 4 * q, v);
        }
    };

    stage(0, sm);
    __syncthreads();

    const int w = tid >> 6, l = tid & 63, le = l & 31, g = l >> 5;

    // layer 3: K=768 in 3 chunks of 256
    f32x16 acc[2]; zero16(acc[0]); zero16(acc[1]);
    {
        const s16x8* Ah = reinterpret_cast<const s16x8*>(w34_h);
        const s16x8* Al = reinterpret_cast<const s16x8*>(w34_l);
        #pragma unroll
        for (int c = 0; c < 3; ++c) {
            char* cur = sm + (c & 1) * 32768;
            char* oth = sm + ((c + 1) & 1) * 32768;
            if (c < 2) stage(c + 1, oth);        // overlap staging with MFMA
            #pragma unroll
            for (int ksl = 0; ksl < 16; ++ksl) {
                int ks = c * 16 + ksl;
                s16x8 AH[2], AL[2], bh, bl;
                #pragma unroll
                for (int mt = 0; mt < 2; ++mt) {
                    int idx = ks * 1024 + (w * 64 + 32 * mt + le) * 2 + g;   // N=512
                    AH[mt] = Ah[idx]; AL[mt] = Al[idx];
                }
                bread<512>(cur, cur + 16384, le, ksl * 32 + 16 * g, bh, bl);
                #pragma unroll
                for (int mt = 0; mt < 2; ++mt) mfma3(acc[mt], AH[mt], AL[mt], bh, bl);
            }
            __syncthreads();
        }
    }

    {   // bias + deg*b23 + relu -> H overlay (32 rows x 1024B stride, hi @0 / lo @32768)
        const float4* b34  = reinterpret_cast<const float4*>(b3);
        const float4* b234 = reinterpret_cast<const float4*>(b23);
        const float degv = (float)sDeg[le];
        #pragma unroll
        for (int mt = 0; mt < 2; ++mt)
            #pragma unroll
            for (int rq = 0; rq < 4; ++rq) {
                int hcol = w * 64 + 32 * mt + 4 * g + 8 * rq;
                float4 bq = b34[hcol >> 2], cq = b234[hcol >> 2];
                float4 gv;
                gv.x = fmaxf(acc[mt][4*rq+0] + bq.x + degv * cq.x, 0.f);
                gv.y = fmaxf(acc[mt][4*rq+1] + bq.y + degv * cq.y, 0.f);
                gv.z = fmaxf(acc[mt][4*rq+2] + bq.z + degv * cq.z, 0.f);
                gv.w = fmaxf(acc[mt][4*rq+3] + bq.w + degv * cq.w, 0.f);
                stash_quad<1024>(sm, sm + 32768, le, hcol, gv);
            }
    }
    __syncthreads();

    // layer 4: K=512, N=256 (one 32-col slice per wave)
    f32x16 a2; zero16(a2);
    {
        const s16x8* Ah = reinterpret_cast<const s16x8*>(w4_h);
        const s16x8* Al = reinterpret_cast<const s16x8*>(w4_l);
        for (int ks = 0; ks < 32; ++ks) {
            s16x8 AH, AL, bh, bl;
            int idx = ks * 512 + (w * 32 + le) * 2 + g;   // N=256
            AH = Ah[idx]; AL = Al[idx];
            bread<1024>(sm, sm + 32768, le, ks * 32 + 16 * g, bh, bl);
            mfma3(a2, AH, AL, bh, bl);
        }
    }

    const float4* b44 = reinterpret_cast<const float4*>(b4);
    float4* out4 = reinterpret_cast<float4*>(out);
    #pragma unroll
    for (int rq = 0; rq < 4; ++rq) {
        int n0 = w * 32 + 4 * g + 8 * rq;
        float4 bq  = b44[n0 >> 2];
        float4 res = nf4[(size_t)(nb + le) * 64 + (n0 >> 2)];
        float4 o;
        o.x = res.x + a2[4*rq+0] + bq.x;
        o.y = res.y + a2[4*rq+1] + bq.y;
        o.z = res.z + a2[4*rq+2] + bq.z;
        o.w = res.w + a2[4*rq+3] + bq.w;
        out4[(size_t)(nb + le) * 64 + (n0 >> 2)] = o;
    }
}

extern "C" void kernel_launch(void* const* d_in, const int* in_sizes, int n_in,
                              void* d_out, int out_size, void* d_ws, size_t ws_size,
                              hipStream_t stream) {
    const float* nf = (const float*)d_in[0];
    const int*   ei = (const int*)d_in[1];
    const float* ef = (const float*)d_in[2];
    const float* W1 = (const float*)d_in[3];
    const float* b1 = (const float*)d_in[4];
    const float* W2 = (const float*)d_in[5];
    const float* b2 = (const float*)d_in[6];
    const float* W3 = (const float*)d_in[7];
    const float* b3 = (const float*)d_in[8];
    const float* W4 = (const float*)d_in[9];
    const float* b4 = (const float*)d_in[10];
    float* out = (float*)d_out;

    // workspace layout (total ~128.7 MB)
    char* ws = (char*)d_ws;
    float* P      = (float*)(ws + 0);               // 20000x1024 fp32
    float* aggH   = (float*)(ws + 81920000);        // 20000x512  fp32
    us16*  wab_h  = (us16*)(ws + 122880000);
    us16*  wab_l  = (us16*)(ws + 123404288);
    us16*  wc_h   = (us16*)(ws + 123928576);
    us16*  wc_l   = (us16*)(ws + 123994112);
    us16*  w34_h  = (us16*)(ws + 124059648);
    us16*  w34_l  = (us16*)(ws + 124846080);
    us16*  w4_h   = (us16*)(ws + 125632512);
    us16*  w4_l   = (us16*)(ws + 125894656);
    float* W23    = (float*)(ws + 126156800);       // 512x512 fp32
    float* b23    = (float*)(ws + 127205376);       // 512 fp32
    int*   deg    = (int*)  (ws + 127207424);       // 20000
    int*   cursor = (int*)  (ws + 127287424);       // 20000
    int*   offs   = (int*)  (ws + 127367424);       // 20001
    int*   csr    = (int*)  (ws + 127447440);       // 320000

    const int* src = ei;                 // edge_index[0]
    const int* tgt = ei + NUM_EDGES;     // edge_index[1]

    (void)hipFuncSetAttribute(reinterpret_cast<const void*>(&edge_csr),
                              hipFuncAttributeMaxDynamicSharedMemorySize, 73728);
    (void)hipFuncSetAttribute(reinterpret_cast<const void*>(&node_mlp),
                              hipFuncAttributeMaxDynamicSharedMemorySize, 65536);
    (void)hipFuncSetAttribute(reinterpret_cast<const void*>(&gemm_p),
                              hipFuncAttributeMaxDynamicSharedMemorySize, 65536);

    hipMemsetAsync(deg, 0, 160000, stream);                       // deg + cursor
    hipMemsetAsync(aggH, 0, (size_t)NUM_NODES * HIDDEN * 4, stream);

    build_deg<<<1250, 256, 0, stream>>>(tgt, deg);
    scan_deg<<<1, 1024, 0, stream>>>(deg, offs);
    fill_csr<<<1250, 256, 0, stream>>>(tgt, offs, cursor, csr);

    compute_w23<<<dim3(513, 2), 256, 0, stream>>>(W2, b2, W3, W23, b23);
    prep_planes<<<3200, 256, 0, stream>>>(W1, W3, W4, W23,
                                          wab_h, wab_l, wc_h, wc_l,
                                          w34_h, w34_l, w4_h, w4_l);

    gemm_p<<<dim3(313, 2), 512, 65536, stream>>>(nf, wab_h, wab_l, P);
    edge_csr<<<5000, 512, 73728, stream>>>(src, tgt, csr, ef, wc_h, wc_l, b1, P, aggH);
    node_mlp<<<625, 512, 65536, stream>>>(nf, aggH, deg, w34_h, w34_l,
                                          w4_h, w4_l, b3, b23, b4, out);
}